// Round 1
// baseline (89.829 us; speedup 1.0000x reference)
//
#include <hip/hip_runtime.h>

// out[b,g] = sum_n x[b,g,n] * W[g,n] + bias[g]
// x: [BATCH, 368, 16] f32, W: [368,16] f32, bias: [368] f32, out: [BATCH, 368] f32
// Memory-bound: ~410 MB HBM traffic/call -> roofline ~65us at 6.3 TB/s.

#define NGROUPS 368
#define NMODELS 16

__global__ __launch_bounds__(256) void ensemble_kernel(
    const float* __restrict__ x,
    const float* __restrict__ W,
    const float* __restrict__ bias,
    float* __restrict__ out,
    int batch)
{
    // Each thread handles 4 batch rows (same g) spaced batch/4 apart,
    // so W[g,:] is loaded once per thread and x loads stay wave-contiguous.
    const int rows = batch >> 2;                 // batch/4 (16384/4 = 4096)
    const int total = rows * NGROUPS;            // work items
    const int stride = gridDim.x * blockDim.x;

    for (int idx = blockIdx.x * blockDim.x + threadIdx.x; idx < total; idx += stride) {
        const int g  = idx % NGROUPS;
        const int b0 = idx / NGROUPS;

        // W[g, 0..15] as 4x float4 (64 B, L2-resident)
        const float4* wp = reinterpret_cast<const float4*>(W + (size_t)g * NMODELS);
        const float4 w0 = wp[0], w1 = wp[1], w2 = wp[2], w3 = wp[3];
        const float bg = bias[g];

        #pragma unroll
        for (int j = 0; j < 4; ++j) {
            const int bb = b0 + j * rows;
            const size_t base = ((size_t)bb * NGROUPS + g) * NMODELS;
            const float4* xp = reinterpret_cast<const float4*>(x + base);
            const float4 x0 = xp[0], x1 = xp[1], x2 = xp[2], x3 = xp[3];

            float s = x0.x * w0.x + x0.y * w0.y + x0.z * w0.z + x0.w * w0.w;
            s += x1.x * w1.x + x1.y * w1.y + x1.z * w1.z + x1.w * w1.w;
            s += x2.x * w2.x + x2.y * w2.y + x2.z * w2.z + x2.w * w2.w;
            s += x3.x * w3.x + x3.y * w3.y + x3.z * w3.z + x3.w * w3.w;

            out[(size_t)bb * NGROUPS + g] = s + bg;
        }
    }
}

extern "C" void kernel_launch(void* const* d_in, const int* in_sizes, int n_in,
                              void* d_out, int out_size, void* d_ws, size_t ws_size,
                              hipStream_t stream)
{
    const float* x    = (const float*)d_in[0];
    const float* W    = (const float*)d_in[1];
    const float* bias = (const float*)d_in[2];
    float* out = (float*)d_out;

    const int batch = in_sizes[0] / (NGROUPS * NMODELS);   // 16384

    const int rows  = batch >> 2;
    const int total = rows * NGROUPS;
    int blocks = (total + 255) / 256;
    if (blocks > 2048) blocks = 2048;   // grid-stride; 256 CU x 8 blocks/CU

    ensemble_kernel<<<blocks, 256, 0, stream>>>(x, W, bias, out, batch);
}

// Round 2
// 89.024 us; speedup vs baseline: 1.0090x; 1.0090x over previous
//
#include <hip/hip_runtime.h>

// out[b,g] = sum_n x[b,g,n] * W[g,n] + bias[g]
// x: [16384, 368, 16] f32, W: [368,16] f32, bias: [368] f32, out: [16384,368] f32
// Memory-bound: ~410 MB HBM/call -> roofline ~58-62 us at ~6.9 TB/s achieved.
//
// Layout: flat float4 index f over x. Lane loads x4[f] (16 B, fully coalesced:
// consecutive lanes -> consecutive 16 B). Four consecutive lanes hold the four
// quarters of one (b,g) row (q = f&3 = tid&3, loop-invariant since grid stride
// is a multiple of 4). Partial dots reduced across the 4-lane group with two
// shfl_xor; lane q==0 adds bias and stores (16 active lanes, contiguous 64 B).
// W (23.5 KB) + bias (1.5 KB) stay L1-resident.

#define NGROUPS 368

__global__ __launch_bounds__(256) void ensemble_kernel(
    const float4* __restrict__ x4,
    const float4* __restrict__ w4,
    const float* __restrict__ bias,
    float* __restrict__ out,
    int totf4)
{
    const int tid    = blockIdx.x * 256 + threadIdx.x;
    const int stride = gridDim.x * 256;
    const int q      = tid & 3;          // quarter of the row this lane owns

    #pragma unroll 4
    for (int f = tid; f < totf4; f += stride) {
        const float4 xv = x4[f];
        const int o = f >> 2;            // flat output index b*368+g
        const int g = o % NGROUPS;       // magic-mul mod
        const float4 wv = w4[(g << 2) | q];

        float s = xv.x * wv.x + xv.y * wv.y + xv.z * wv.z + xv.w * wv.w;
        s += __shfl_xor(s, 1);
        s += __shfl_xor(s, 2);

        if (q == 0) {
            out[o] = s + bias[g];
        }
    }
}

extern "C" void kernel_launch(void* const* d_in, const int* in_sizes, int n_in,
                              void* d_out, int out_size, void* d_ws, size_t ws_size,
                              hipStream_t stream)
{
    const float4* x4   = (const float4*)d_in[0];
    const float4* w4   = (const float4*)d_in[1];
    const float* bias  = (const float*)d_in[2];
    float* out = (float*)d_out;

    const int totf4 = in_sizes[0] >> 2;   // 24,117,248 float4 loads

    int blocks = (totf4 + 255) / 256;
    if (blocks > 2048) blocks = 2048;     // grid-stride; 256 CU x 8 blocks/CU

    ensemble_kernel<<<blocks, 256, 0, stream>>>(x4, w4, bias, out, totf4);
}